// Round 3
// baseline (648.888 us; speedup 1.0000x reference)
//
#include <hip/hip_runtime.h>
#include <math.h>

#define TPTS 32            // points per block tile
#define H1   100           // taskmap / vs hidden
#define H3   300           // vv hidden
#define SA   136           // row stride (bf16) taskmap-phase (K=128 pad + 8 skew)
#define SV   328           // row stride (bf16) vv-phase (K=320 pad + 8)
#define BIGN 13056         // max(96*SA, 32*SV)

// bf16 W^T regions inside d_ws (element offsets into short* at byte 64)
#define WT_TM1 0
#define WT_TM2 14336       // 112*128
#define WT_VS  28672
#define WT_VV  43008       // then 304*320
#define WT_TOTAL (43008 + 97280)

typedef __attribute__((ext_vector_type(8))) short s8v;   // 8 bf16
typedef __attribute__((ext_vector_type(4))) float f4v;   // MFMA accumulator

__device__ __forceinline__ float eluf(float v)      { return v > 0.f ? v : expm1f(v); }
__device__ __forceinline__ float softplusf(float v) { return v > 20.f ? v : log1pf(expf(v)); }
__device__ __forceinline__ float leakyf(float v)    { return v >= 0.f ? v : 0.01f * v; }
__device__ __forceinline__ float preluf(float v, float a) { return v >= 0.f ? v : a * v; }

__device__ __forceinline__ short f2bf(float f) {
    union { float f; unsigned u; } v; v.f = f;
    unsigned r = v.u + 0x7fffu + ((v.u >> 16) & 1u);   // RNE
    return (short)(r >> 16);
}
__device__ __forceinline__ float bf2f(short s) {
    union { unsigned u; float f; } v; v.u = ((unsigned)(unsigned short)s) << 16; return v.f;
}

// ---------------------------------------------------------------------------
// prep (blocks 0..547): fp32 W[K][N] -> bf16 W^T[Npad][Kpad] zero-padded.
// origin (block 548): origin_y = taskmap(zeros(1,2)), fp32.
// ---------------------------------------------------------------------------
__global__ void ngdv_prep(
    const float* __restrict__ tm1_w1, const float* __restrict__ tm1_b1,
    const float* __restrict__ tm1_w2, const float* __restrict__ tm1_b2,
    const float* __restrict__ tm1_w3, const float* __restrict__ tm1_b3,
    const float* __restrict__ tm2_w1, const float* __restrict__ tm2_b1,
    const float* __restrict__ tm2_w2, const float* __restrict__ tm2_b2,
    const float* __restrict__ tm2_w3, const float* __restrict__ tm2_b3,
    const float* __restrict__ vs_w2,  const float* __restrict__ vv_w2,
    short* __restrict__ outw, float* __restrict__ origin_out)
{
    __shared__ float h1[H1], h2[H1], y1o[2], g1[H1], g2[H1];
    const int tid = threadIdx.x;
    if (blockIdx.x < 548) {
        int idx = blockIdx.x * 256 + tid;
        if (idx < 3 * 14336) {
            int rgn = idx / 14336, r = idx % 14336;
            int n = r / 128, k = r % 128;
            const float* src = (rgn == 0) ? tm1_w2 : (rgn == 1) ? tm2_w2 : vs_w2;
            float v = (n < H1 && k < H1) ? src[k * H1 + n] : 0.f;
            outw[rgn * 14336 + n * 128 + k] = f2bf(v);
        } else if (idx < WT_TOTAL) {
            int r = idx - 3 * 14336;
            int n = r / 320, k = r % 320;
            float v = (n < H3 && k < H3) ? vv_w2[k * H3 + n] : 0.f;
            outw[WT_VV + n * 320 + k] = f2bf(v);
        }
        return;
    }
    // origin block
    if (tid < H1) h1[tid] = tanhf(tm1_b1[tid]);
    __syncthreads();
    if (tid < H1) {
        float acc = tm1_b2[tid];
        for (int k = 0; k < H1; ++k) acc += h1[k] * tm1_w2[k*H1 + tid];
        h2[tid] = tanhf(acc);
    }
    __syncthreads();
    if (tid < 2) {
        float acc = tm1_b3[tid];
        for (int k = 0; k < H1; ++k) acc += h2[k] * tm1_w3[k*2 + tid];
        y1o[tid] = acc;
    }
    __syncthreads();
    if (tid < H1) g1[tid] = eluf(tm2_b1[tid] + y1o[0]*tm2_w1[tid] + y1o[1]*tm2_w1[H1 + tid]);
    __syncthreads();
    if (tid < H1) {
        float acc = tm2_b2[tid];
        for (int k = 0; k < H1; ++k) acc += g1[k] * tm2_w2[k*H1 + tid];
        g2[tid] = eluf(acc);
    }
    __syncthreads();
    if (tid < 2) {
        float acc = tm2_b3[tid];
        for (int k = 0; k < H1; ++k) acc += g2[k] * tm2_w3[k*2 + tid];
        origin_out[tid] = (1.f + softplusf(acc)) * y1o[tid];
    }
}

// ---------------------------------------------------------------------------
// GEMM tiles, swapped operands: acc = mfma(Bfrag, Afrag) computes C^T, so the
// 4 accumulator values are 4 CONSECUTIVE COLUMNS of one point-row -> one
// packed ds_write_b64 per tile. Flat (nt,mt) traversal over 8 waves.
//   point row = mt*16 + (lane&15);  cols = nt*16 + (lane>>4)*4 + reg
// ---------------------------------------------------------------------------
template <int KSTEPS, int MT>
__device__ __forceinline__ void gemm_tiles(const short* Ain, short* Cout,
    const short* __restrict__ wT, int ntiles, int astride, int Kpad,
    int fm, int fq, int wv)
{
    const int total = ntiles * MT;
    for (int t = wv; t < total; t += 8) {
        int nt = t / MT, mt = t % MT;
        const short* bp = wT + (nt*16 + fm) * Kpad + fq*8;
        const short* ap = Ain + (mt*16 + fm) * astride + fq*8;
        f4v acc = {0.f, 0.f, 0.f, 0.f};
        #pragma unroll
        for (int ks = 0; ks < KSTEPS; ++ks) {
            s8v b = *(const s8v*)(bp + ks*32);
            s8v a = *(const s8v*)(ap + ks*32);
            acc = __builtin_amdgcn_mfma_f32_16x16x32_bf16(b, a, acc, 0, 0, 0);
        }
        uint2 pk;
        pk.x = ((unsigned)(unsigned short)f2bf(acc[0])) | (((unsigned)(unsigned short)f2bf(acc[1])) << 16);
        pk.y = ((unsigned)(unsigned short)f2bf(acc[2])) | (((unsigned)(unsigned short)f2bf(acc[3])) << 16);
        *(uint2*)&Cout[(mt*16 + fm) * astride + nt*16 + fq*4] = pk;
    }
}

// ---------------------------------------------------------------------------
// Main fused kernel: 512 threads, 32 points/block. Taskmap GEMMs run M=96
// (primal rows 0..31, tangent d0 rows 32..63, d1 rows 64..95).
// ---------------------------------------------------------------------------
__global__ __launch_bounds__(512, 4) void ngdv_main(
    const float* __restrict__ x,
    const float* __restrict__ tm1_w1, const float* __restrict__ tm1_b1,
    const float* __restrict__ tm1_b2,
    const float* __restrict__ tm1_w3, const float* __restrict__ tm1_b3,
    const float* __restrict__ tm2_w1, const float* __restrict__ tm2_b1,
    const float* __restrict__ tm2_b2,
    const float* __restrict__ tm2_w3, const float* __restrict__ tm2_b3,
    const float* __restrict__ vv_w1, const float* __restrict__ vv_b1, const float* __restrict__ vv_a1,
    const float* __restrict__ vv_b2, const float* __restrict__ vv_a2,
    const float* __restrict__ vv_w3, const float* __restrict__ vv_b3,
    const float* __restrict__ vs_w1, const float* __restrict__ vs_b1,
    const float* __restrict__ vs_b2,
    const float* __restrict__ vs_w3, const float* __restrict__ vs_b3,
    const short* __restrict__ wsb,   const float* __restrict__ origin,
    float* __restrict__ out, int npts)
{
    __shared__ short U[BIGN];
    __shared__ short V[BIGN];
    __shared__ float xs[64], y1s[64], dy1s[128], dss[128], ss[64], sigs[64],
                     ys[64], Js[128], lvs[32], dotys[64], w3s[600];

    const int tid  = threadIdx.x;
    const int p0   = blockIdx.x * TPTS;
    const int wv   = tid >> 6;
    const int lane = tid & 63;
    const int fm   = lane & 15;
    const int fq   = lane >> 4;
    const int j    = tid & 127;
    const int th   = tid >> 7;          // 0..3 -> 8 points each
    const int ep   = tid >> 4;          // epilogue: point 0..31
    const int ec   = tid & 15;          // epilogue: col-group 0..15
    const float a1v = vv_a1[0], a2v = vv_a2[0];

    // ---- S0: x tile
    if (tid < 64) { int g = p0*2 + tid; xs[tid] = (g < npts*2) ? x[g] : 0.f; }
    __syncthreads();

    // ---- S1: tm1 L1 (2->100) + tangent seeds -> U(96 rows); stage tm1_w3
    if (tid < 200) w3s[tid] = tm1_w3[tid];
    {
        bool valid = j < H1;
        float w0 = 0.f, w1 = 0.f, b = 0.f;
        if (valid) { w0 = tm1_w1[j]; w1 = tm1_w1[H1 + j]; b = tm1_b1[j]; }
        #pragma unroll
        for (int tt = 0; tt < 8; ++tt) {
            int p = th*8 + tt;
            if (valid) {
                float pre = fmaf(xs[p*2+1], w1, fmaf(xs[p*2], w0, b));
                float h = tanhf(pre), dd = 1.f - h*h;
                U[p*SA + j] = f2bf(h);
                U[(32+p)*SA + j] = f2bf(w0*dd);
                U[(64+p)*SA + j] = f2bf(w1*dd);
            } else {
                U[p*SA + j] = 0; U[(32+p)*SA + j] = 0; U[(64+p)*SA + j] = 0;
            }
        }
    }
    __syncthreads();

    // ---- G1: [96x128] @ tm1_w2 -> V
    gemm_tiles<4, 6>(U, V, wsb + WT_TM1, 7, SA, 128, fm, fq, wv);
    __syncthreads();

    // ---- E1: fused tanh + tangent*(1-h^2), vectorized 8 cols/thread
    {
        int col0 = ec * 8;
        s8v vp  = *(const s8v*)&V[ep*SA + col0];
        s8v vt0 = *(const s8v*)&V[(32+ep)*SA + col0];
        s8v vt1 = *(const s8v*)&V[(64+ep)*SA + col0];
        s8v up, ut0, ut1;
        #pragma unroll
        for (int e = 0; e < 8; ++e) {
            int col = col0 + e;
            bool valid = col < H1;
            float h = valid ? tanhf(bf2f(vp[e]) + tm1_b2[valid ? col : 0]) : 0.f;
            float dd = 1.f - h*h;
            up[e]  = f2bf(h);
            ut0[e] = valid ? f2bf(bf2f(vt0[e]) * dd) : (short)0;
            ut1[e] = valid ? f2bf(bf2f(vt1[e]) * dd) : (short)0;
        }
        *(s8v*)&U[ep*SA + col0] = up;
        *(s8v*)&U[(32+ep)*SA + col0] = ut0;
        *(s8v*)&U[(64+ep)*SA + col0] = ut1;
    }
    __syncthreads();

    // ---- S2: tm1 L3 (100->2): y1, dy1(+I).  384 threads, k split in halves.
    if (tid < 384) {
        int r = tid >> 2, i = (tid >> 1) & 1, hf = tid & 1;
        float acc = 0.f;
        int k0 = hf ? 48 : 0, k1 = hf ? 96 : 48;
        for (int k = k0; k < k1; k += 8) {
            s8v av = *(const s8v*)&U[r*SA + k];
            #pragma unroll
            for (int e = 0; e < 8; ++e) acc = fmaf(bf2f(av[e]), w3s[(k+e)*2 + i], acc);
        }
        if (hf) for (int k = 96; k < 100; ++k) acc = fmaf(bf2f(U[r*SA + k]), w3s[k*2 + i], acc);
        acc += __shfl_xor(acc, 1, 64);
        if (!hf) {
            if (r < 32) y1s[r*2 + i] = acc + tm1_b3[i] + xs[r*2 + i];
            else { int d = (r-32) >> 5, p = (r-32) & 31; dy1s[p*4 + d*2 + i] = acc + ((d == i) ? 1.f : 0.f); }
        }
    }
    __syncthreads();

    // ---- S3: tm2 L1 (2->100) + tangent -> U ; stage tm2_w3
    if (tid < 200) w3s[tid] = tm2_w3[tid];
    {
        bool valid = j < H1;
        float w0 = 0.f, w1 = 0.f, b = 0.f;
        if (valid) { w0 = tm2_w1[j]; w1 = tm2_w1[H1 + j]; b = tm2_b1[j]; }
        #pragma unroll
        for (int tt = 0; tt < 8; ++tt) {
            int p = th*8 + tt;
            if (valid) {
                float pre = fmaf(y1s[p*2+1], w1, fmaf(y1s[p*2], w0, b));
                float g = eluf(pre), dd = (pre > 0.f) ? 1.f : (g + 1.f);
                U[p*SA + j] = f2bf(g);
                U[(32+p)*SA + j] = f2bf((dy1s[p*4+0]*w0 + dy1s[p*4+1]*w1) * dd);
                U[(64+p)*SA + j] = f2bf((dy1s[p*4+2]*w0 + dy1s[p*4+3]*w1) * dd);
            } else {
                U[p*SA + j] = 0; U[(32+p)*SA + j] = 0; U[(64+p)*SA + j] = 0;
            }
        }
    }
    __syncthreads();

    // ---- G2: [96x128] @ tm2_w2 -> V
    gemm_tiles<4, 6>(U, V, wsb + WT_TM2, 7, SA, 128, fm, fq, wv);
    __syncthreads();

    // ---- E2: fused elu + tangent*elu'
    {
        int col0 = ec * 8;
        s8v vp  = *(const s8v*)&V[ep*SA + col0];
        s8v vt0 = *(const s8v*)&V[(32+ep)*SA + col0];
        s8v vt1 = *(const s8v*)&V[(64+ep)*SA + col0];
        s8v up, ut0, ut1;
        #pragma unroll
        for (int e = 0; e < 8; ++e) {
            int col = col0 + e;
            bool valid = col < H1;
            float pre = valid ? (bf2f(vp[e]) + tm2_b2[valid ? col : 0]) : 0.f;
            float g = valid ? eluf(pre) : 0.f;
            float dd = (pre > 0.f) ? 1.f : (g + 1.f);
            up[e]  = f2bf(g);
            ut0[e] = valid ? f2bf(bf2f(vt0[e]) * dd) : (short)0;
            ut1[e] = valid ? f2bf(bf2f(vt1[e]) * dd) : (short)0;
        }
        *(s8v*)&U[ep*SA + col0] = up;
        *(s8v*)&U[(32+ep)*SA + col0] = ut0;
        *(s8v*)&U[(64+ep)*SA + col0] = ut1;
    }
    __syncthreads();

    // ---- S4: tm2 L3 (100->2): s, sigma, ds
    if (tid < 384) {
        int r = tid >> 2, i = (tid >> 1) & 1, hf = tid & 1;
        float acc = 0.f;
        int k0 = hf ? 48 : 0, k1 = hf ? 96 : 48;
        for (int k = k0; k < k1; k += 8) {
            s8v av = *(const s8v*)&U[r*SA + k];
            #pragma unroll
            for (int e = 0; e < 8; ++e) acc = fmaf(bf2f(av[e]), w3s[(k+e)*2 + i], acc);
        }
        if (hf) for (int k = 96; k < 100; ++k) acc = fmaf(bf2f(U[r*SA + k]), w3s[k*2 + i], acc);
        acc += __shfl_xor(acc, 1, 64);
        if (!hf) {
            if (r < 32) {
                float spre = acc + tm2_b3[i];
                ss[r*2 + i] = softplusf(spre);
                sigs[r*2 + i] = 1.f / (1.f + expf(-spre));
            } else { int d = (r-32) >> 5, p = (r-32) & 31; dss[p*4 + d*2 + i] = acc; }
        }
    }
    __syncthreads();

    // ---- S4b: J, y
    if (tid < 128) {
        int t = tid >> 2, d = (tid >> 1) & 1, i = tid & 1;
        float dsv = dss[t*4 + d*2 + i] * sigs[t*2 + i];
        Js[t*4 + i*2 + d] = dsv * y1s[t*2 + i] + (1.f + ss[t*2 + i]) * dy1s[t*4 + d*2 + i];
    } else if (tid >= 192 && tid < 256) {
        int r = tid - 192, t = r >> 1, i = r & 1;
        ys[t*2 + i] = (1.f + ss[t*2 + i]) * y1s[t*2 + i] - origin[i];
    }
    __syncthreads();

    // ---- S5: vs L1 (2->100) -> U rows 0..31 ; stage vs_w3
    if (tid < 100) w3s[tid] = vs_w3[tid];
    {
        bool valid = j < H1;
        float w0 = 0.f, w1 = 0.f, b = 0.f;
        if (valid) { w0 = vs_w1[j]; w1 = vs_w1[H1 + j]; b = vs_b1[j]; }
        #pragma unroll
        for (int tt = 0; tt < 8; ++tt) {
            int p = th*8 + tt;
            float pre = fmaf(xs[p*2+1], w1, fmaf(xs[p*2], w0, b));
            U[p*SA + j] = valid ? f2bf(leakyf(pre)) : (short)0;
        }
    }
    __syncthreads();

    // ---- G3: [32x128] @ vs_w2 -> V
    gemm_tiles<4, 2>(U, V, wsb + WT_VS, 7, SA, 128, fm, fq, wv);
    __syncthreads();

    // ---- E3: leaky epilogue (primal only)
    {
        int col0 = ec * 8;
        s8v vp = *(const s8v*)&V[ep*SA + col0];
        s8v up;
        #pragma unroll
        for (int e = 0; e < 8; ++e) {
            int col = col0 + e;
            bool valid = col < H1;
            up[e] = valid ? f2bf(leakyf(bf2f(vp[e]) + vs_b2[valid ? col : 0])) : (short)0;
        }
        *(s8v*)&U[ep*SA + col0] = up;
    }
    __syncthreads();

    // ---- S6: vs L3 (100->1) -> lvs.  64 threads, half-split.
    if (tid < 64) {
        int t = tid >> 1, hf = tid & 1;
        float acc = 0.f;
        int k0 = hf ? 48 : 0, k1 = hf ? 96 : 48;
        for (int k = k0; k < k1; k += 8) {
            s8v av = *(const s8v*)&U[t*SA + k];
            #pragma unroll
            for (int e = 0; e < 8; ++e) acc = fmaf(bf2f(av[e]), w3s[k+e], acc);
        }
        if (hf) for (int k = 96; k < 100; ++k) acc = fmaf(bf2f(U[t*SA + k]), w3s[k], acc);
        acc += __shfl_xor(acc, 1, 64);
        if (!hf) lvs[t] = acc + vs_b3[0];
    }
    __syncthreads();

    // ---- S7: vv L1 (2->300) -> U rows 0..31 (stride SV); stage vv_w3
    for (int q = tid; q < 600; q += 512) w3s[q] = vv_w3[q];
    for (int base = 0; base < 320; base += 128) {
        int jj0 = base + ec*8;
        if (jj0 < 320) {
            float y0 = ys[ep*2], y1v = ys[ep*2+1];
            s8v hv;
            #pragma unroll
            for (int e = 0; e < 8; ++e) {
                int jj = jj0 + e;
                bool valid = jj < H3;
                float val = 0.f;
                if (valid) {
                    float pre = fmaf(y1v, vv_w1[H3 + jj], fmaf(y0, vv_w1[jj], vv_b1[jj]));
                    val = preluf(pre, a1v);
                }
                hv[e] = f2bf(val);
            }
            *(s8v*)&U[ep*SV + jj0] = hv;
        }
    }
    __syncthreads();

    // ---- G4: [32x320] @ vv_w2 -> V
    gemm_tiles<10, 2>(U, V, wsb + WT_VV, 19, SV, 320, fm, fq, wv);
    __syncthreads();

    // ---- E4: prelu(.,a2) epilogue
    for (int base = 0; base < 320; base += 128) {
        int jj0 = base + ec*8;
        if (jj0 < 320) {
            s8v vp = *(const s8v*)&V[ep*SV + jj0];
            s8v hv;
            #pragma unroll
            for (int e = 0; e < 8; ++e) {
                int jj = jj0 + e;
                bool valid = jj < H3;
                float val = 0.f;
                if (valid) val = preluf(bf2f(vp[e]) + vv_b2[valid ? jj : 0], a2v);
                hv[e] = f2bf(val);
            }
            *(s8v*)&U[ep*SV + jj0] = hv;
        }
    }
    __syncthreads();

    // ---- S8: vv L3 (300->2) -> dotys.  128 threads, half-split over k.
    if (tid < 128) {
        int t = tid >> 2, i = (tid >> 1) & 1, hf = tid & 1;
        float acc = 0.f;
        int k0 = hf ? 152 : 0, k1 = hf ? 296 : 152;
        for (int k = k0; k < k1; k += 8) {
            s8v av = *(const s8v*)&U[t*SV + k];
            #pragma unroll
            for (int e = 0; e < 8; ++e) acc = fmaf(bf2f(av[e]), w3s[(k+e)*2 + i], acc);
        }
        if (hf) for (int k = 296; k < 300; ++k) acc = fmaf(bf2f(U[t*SV + k]), w3s[k*2 + i], acc);
        acc += __shfl_xor(acc, 1, 64);
        if (!hf) dotys[t*2 + i] = acc + vv_b3[i];
    }
    __syncthreads();

    // ---- S9: combine & store
    if (tid < TPTS) {
        int t = tid, p = p0 + t;
        if (p < npts) {
            float y0 = ys[t*2], y1v = ys[t*2+1];
            float dt0 = dotys[t*2], dt1 = dotys[t*2+1];
            float ls = dt0*y0 + dt1*y1v;
            float Vq = y0*y0 + y1v*y1v;
            float coef = fmaxf(ls + 1e-4f*Vq, 0.f) / (Vq + 1e-12f);
            float yd0 = dt0 - coef*y0, yd1 = dt1 - coef*y1v;
            float nrm = sqrtf(yd0*yd0 + yd1*yd1);
            float inv_n = 1.f / fmaxf(nrm, 1e-12f);
            float yn0 = yd0*inv_n, yn1 = yd1*inv_n;
            float Ja = Js[t*4+0], Jb = Js[t*4+1], Jc = Js[t*4+2], Jd = Js[t*4+3];
            float invdet = 1.f / (Ja*Jd - Jb*Jc);
            float xh0 = ( Jd*yn0 - Jb*yn1) * invdet;
            float xh1 = (-Jc*yn0 + Ja*yn1) * invdet;
            float lv = lvs[t];
            float2 o;
            o.x = (expf(lv + xs[t*2+0]) + 1e-12f) * xh0;
            o.y = (expf(lv + xs[t*2+1]) + 1e-12f) * xh1;
            *(float2*)&out[p*2] = o;
        }
    }
}

extern "C" void kernel_launch(void* const* d_in, const int* in_sizes, int n_in,
                              void* d_out, int out_size, void* d_ws, size_t ws_size,
                              hipStream_t stream) {
    const float* x      = (const float*)d_in[0];
    const float* tm1_w1 = (const float*)d_in[1];
    const float* tm1_b1 = (const float*)d_in[2];
    const float* tm1_w2 = (const float*)d_in[3];
    const float* tm1_b2 = (const float*)d_in[4];
    const float* tm1_w3 = (const float*)d_in[5];
    const float* tm1_b3 = (const float*)d_in[6];
    const float* tm2_w1 = (const float*)d_in[7];
    const float* tm2_b1 = (const float*)d_in[8];
    const float* tm2_w2 = (const float*)d_in[9];
    const float* tm2_b2 = (const float*)d_in[10];
    const float* tm2_w3 = (const float*)d_in[11];
    const float* tm2_b3 = (const float*)d_in[12];
    const float* vv_w1  = (const float*)d_in[13];
    const float* vv_b1  = (const float*)d_in[14];
    const float* vv_a1  = (const float*)d_in[15];
    const float* vv_w2  = (const float*)d_in[16];
    const float* vv_b2  = (const float*)d_in[17];
    const float* vv_a2  = (const float*)d_in[18];
    const float* vv_w3  = (const float*)d_in[19];
    const float* vv_b3  = (const float*)d_in[20];
    const float* vs_w1  = (const float*)d_in[21];
    const float* vs_b1  = (const float*)d_in[22];
    const float* vs_w2  = (const float*)d_in[23];
    const float* vs_b2  = (const float*)d_in[24];
    const float* vs_w3  = (const float*)d_in[25];
    const float* vs_b3  = (const float*)d_in[26];

    float* out       = (float*)d_out;
    float* origin_ws = (float*)d_ws;                       // 2 floats
    short* wsb       = (short*)((char*)d_ws + 64);         // bf16 W^T regions
    const int npts = in_sizes[0] / 2;
    const int nblk = (npts + TPTS - 1) / TPTS;

    ngdv_prep<<<549, 256, 0, stream>>>(
        tm1_w1, tm1_b1, tm1_w2, tm1_b2, tm1_w3, tm1_b3,
        tm2_w1, tm2_b1, tm2_w2, tm2_b2, tm2_w3, tm2_b3,
        vs_w2, vv_w2, wsb, origin_ws);

    ngdv_main<<<nblk, 512, 0, stream>>>(
        x,
        tm1_w1, tm1_b1, tm1_b2, tm1_w3, tm1_b3,
        tm2_w1, tm2_b1, tm2_b2, tm2_w3, tm2_b3,
        vv_w1, vv_b1, vv_a1, vv_b2, vv_a2, vv_w3, vv_b3,
        vs_w1, vs_b1, vs_b2, vs_w3, vs_b3,
        wsb, origin_ws, out, npts);
}

// Round 5
// 414.047 us; speedup vs baseline: 1.5672x; 1.5672x over previous
//
#include <hip/hip_runtime.h>
#include <math.h>

#define H1 100
#define H3 300
#define SA 136            // taskmap row stride (shorts): K=128 pad + 8 skew
#define SV 328            // vv row stride (shorts): K=320 pad + 8 skew
#define UW 6528           // shorts per wave-private U slice
#define WSW 384           // floats per wave-private scratch

// bf16 regions in d_ws (short-element offsets from byte 64)
#define WT_TM1    0
#define WT_TM2    14336
#define WT_VS     28672
#define WT_VV     43008
#define WT_TM1L3  140288
#define WT_TM2L3  142336
#define WT_VSL3   144384
#define WT_VVL3   146432
#define NSHORT    151552
// fp32 padded small-weight region (float-element offsets)
#define F_TM1W1 0
#define F_TM1B1 256
#define F_TM2W1 384
#define F_TM2B1 640
#define F_VSW1  768
#define F_VSB1  1024
#define F_VVW1  1152
#define F_VVB1  1792
#define F_TM1B2 2112
#define F_TM2B2 2240
#define F_VSB2  2368
#define F_VVB2  2496
#define NFLOAT  2816
// WS scratch layout (floats per wave)
#define WY1 0
#define WDY1 32
#define WSS 96
#define WSG 128
#define WDS 160
#define WJ 224
#define WYS 288
#define WLV 320
#define WDT 336

typedef __attribute__((ext_vector_type(8))) short s8v;
typedef __attribute__((ext_vector_type(4))) float f4v;

__device__ __forceinline__ f4v mfma16(s8v a, s8v b, f4v c) {
    return __builtin_amdgcn_mfma_f32_16x16x32_bf16(a, b, c, 0, 0, 0);
}
__device__ __forceinline__ float rcp_fast(float v) { return __builtin_amdgcn_rcpf(v); }
__device__ __forceinline__ float tanh_fast(float v) {
    float t = __expf(2.f * v);
    return 1.f - 2.f * rcp_fast(t + 1.f);
}
__device__ __forceinline__ float leakyf(float v) { return v >= 0.f ? v : 0.01f * v; }
__device__ __forceinline__ float preluf(float v, float a) { return v >= 0.f ? v : a * v; }
__device__ __forceinline__ short f2bf(float f) {
    union { float f; unsigned u; } v; v.f = f;
    unsigned r = v.u + 0x7fffu + ((v.u >> 16) & 1u);   // RNE
    return (short)(r >> 16);
}
__device__ __forceinline__ uint2 pk4(float v0, float v1, float v2, float v3) {
    uint2 r;
    r.x = ((unsigned)(unsigned short)f2bf(v0)) | (((unsigned)(unsigned short)f2bf(v1)) << 16);
    r.y = ((unsigned)(unsigned short)f2bf(v2)) | (((unsigned)(unsigned short)f2bf(v3)) << 16);
    return r;
}

// ---------------------------------------------------------------------------
// prep: W^T bf16 zero-padded regions + fp32 padded L1 weights/biases + origin
// ---------------------------------------------------------------------------
__global__ void ngdv_prep(
    const float* __restrict__ tm1_w1, const float* __restrict__ tm1_b1,
    const float* __restrict__ tm1_w2, const float* __restrict__ tm1_b2,
    const float* __restrict__ tm1_w3, const float* __restrict__ tm1_b3,
    const float* __restrict__ tm2_w1, const float* __restrict__ tm2_b1,
    const float* __restrict__ tm2_w2, const float* __restrict__ tm2_b2,
    const float* __restrict__ tm2_w3, const float* __restrict__ tm2_b3,
    const float* __restrict__ vs_w1,  const float* __restrict__ vs_b1,
    const float* __restrict__ vs_w2,  const float* __restrict__ vs_b2,
    const float* __restrict__ vs_w3,
    const float* __restrict__ vv_w1,  const float* __restrict__ vv_b1,
    const float* __restrict__ vv_w2,  const float* __restrict__ vv_b2,
    const float* __restrict__ vv_w3,
    short* __restrict__ wsb, float* __restrict__ wsf, float* __restrict__ origin_out)
{
    const int tid = threadIdx.x;
    if (blockIdx.x < 603) {
        int idx = blockIdx.x * 256 + tid;
        if (idx < NSHORT) {
            short o;
            if (idx < WT_TM2)          { int n = idx >> 7, k = idx & 127; o = (n < H1 && k < H1) ? f2bf(tm1_w2[k*H1 + n]) : (short)0; }
            else if (idx < WT_VS)      { int r = idx - WT_TM2,   n = r >> 7, k = r & 127; o = (n < H1 && k < H1) ? f2bf(tm2_w2[k*H1 + n]) : (short)0; }
            else if (idx < WT_VV)      { int r = idx - WT_VS,    n = r >> 7, k = r & 127; o = (n < H1 && k < H1) ? f2bf(vs_w2[k*H1 + n]) : (short)0; }
            else if (idx < WT_TM1L3)   { int r = idx - WT_VV,    n = r / 320, k = r % 320; o = (n < H3 && k < H3) ? f2bf(vv_w2[k*H3 + n]) : (short)0; }
            else if (idx < WT_TM2L3)   { int r = idx - WT_TM1L3, n = r >> 7, k = r & 127; o = (n < 2 && k < H1) ? f2bf(tm1_w3[k*2 + n]) : (short)0; }
            else if (idx < WT_VSL3)    { int r = idx - WT_TM2L3, n = r >> 7, k = r & 127; o = (n < 2 && k < H1) ? f2bf(tm2_w3[k*2 + n]) : (short)0; }
            else if (idx < WT_VVL3)    { int r = idx - WT_VSL3,  n = r >> 7, k = r & 127; o = (n < 1 && k < H1) ? f2bf(vs_w3[k]) : (short)0; }
            else                       { int r = idx - WT_VVL3,  n = r / 320, k = r % 320; o = (n < 2 && k < H3) ? f2bf(vv_w3[k*2 + n]) : (short)0; }
            wsb[idx] = o;
        } else {
            int f = idx - NSHORT;
            if (f < NFLOAT) {
                float v = 0.f;
                if (f < 256)       { int d = f >> 7, c = f & 127; if (c < H1) v = tm1_w1[d*H1 + c]; }
                else if (f < 384)  { int c = f - 256;  if (c < H1) v = tm1_b1[c]; }
                else if (f < 640)  { int r = f - 384, d = r >> 7, c = r & 127; if (c < H1) v = tm2_w1[d*H1 + c]; }
                else if (f < 768)  { int c = f - 640;  if (c < H1) v = tm2_b1[c]; }
                else if (f < 1024) { int r = f - 768, d = r >> 7, c = r & 127; if (c < H1) v = vs_w1[d*H1 + c]; }
                else if (f < 1152) { int c = f - 1024; if (c < H1) v = vs_b1[c]; }
                else if (f < 1792) { int r = f - 1152, d = r / 320, c = r % 320; if (c < H3) v = vv_w1[d*H3 + c]; }
                else if (f < 2112) { int c = f - 1792; if (c < H3) v = vv_b1[c]; }
                else if (f < 2240) { int c = f - 2112; if (c < H1) v = tm1_b2[c]; }
                else if (f < 2368) { int c = f - 2240; if (c < H1) v = tm2_b2[c]; }
                else if (f < 2496) { int c = f - 2368; if (c < H1) v = vs_b2[c]; }
                else               { int c = f - 2496; if (c < H3) v = vv_b2[c]; }
                wsf[f] = v;
            }
        }
        return;
    }
    // origin block: taskmap(0)
    __shared__ float h1[H1], h2[H1], y1o[2], g1[H1], g2[H1];
    if (tid < H1) h1[tid] = tanhf(tm1_b1[tid]);
    __syncthreads();
    if (tid < H1) {
        float acc = tm1_b2[tid];
        for (int k = 0; k < H1; ++k) acc += h1[k] * tm1_w2[k*H1 + tid];
        h2[tid] = tanhf(acc);
    }
    __syncthreads();
    if (tid < 2) {
        float acc = tm1_b3[tid];
        for (int k = 0; k < H1; ++k) acc += h2[k] * tm1_w3[k*2 + tid];
        y1o[tid] = acc;
    }
    __syncthreads();
    if (tid < H1) {
        float pre = tm2_b1[tid] + y1o[0]*tm2_w1[tid] + y1o[1]*tm2_w1[H1 + tid];
        g1[tid] = pre > 0.f ? pre : expm1f(pre);
    }
    __syncthreads();
    if (tid < H1) {
        float acc = tm2_b2[tid];
        for (int k = 0; k < H1; ++k) acc += g1[k] * tm2_w2[k*H1 + tid];
        g2[tid] = acc > 0.f ? acc : expm1f(acc);
    }
    __syncthreads();
    if (tid < 2) {
        float acc = tm2_b3[tid];
        for (int k = 0; k < H1; ++k) acc += g2[k] * tm2_w3[k*2 + tid];
        float s = acc > 20.f ? acc : log1pf(expf(acc));
        origin_out[tid] = (1.f + s) * y1o[tid];
    }
}

// ---------------------------------------------------------------------------
// Main: 256 threads = 4 waves, each wave owns 16 points (wave-private U/WS
// slices). __syncthreads() at every LDS producer->consumer phase boundary
// (R4's barrier-free version NaN'd; barriers are cheap at 4 waves/block).
// ---------------------------------------------------------------------------
__global__ __launch_bounds__(256, 2) void ngdv_main(
    const float* __restrict__ x,
    const float* __restrict__ tm1_b3, const float* __restrict__ tm2_b3,
    const float* __restrict__ vs_b3,  const float* __restrict__ vv_b3,
    const float* __restrict__ vv_a1,  const float* __restrict__ vv_a2,
    const short* __restrict__ wsb,    const float* __restrict__ wsf,
    const float* __restrict__ origin, float* __restrict__ out, int npts)
{
    __shared__ __align__(16) short Uall[4*UW];
    __shared__ float WSall[4*WSW];
    const int tid = threadIdx.x;
    const int wv = tid >> 6, lane = tid & 63;
    const int fm = lane & 15, fq = lane >> 4;
    short* U  = &Uall[wv*UW];
    float* WS = &WSall[wv*WSW];
    const int p = blockIdx.x*64 + wv*16 + fm;
    float2 xv = {0.f, 0.f};
    if (p < npts) xv = *(const float2*)&x[p*2];
    const float a1v = vv_a1[0], a2v = vv_a2[0];

    // zero taskmap pad cols 112..127 (rows 0..47)
    if (lane < 48) {
        s8v z = {0,0,0,0,0,0,0,0};
        *(s8v*)&U[lane*SA + 112] = z;
        *(s8v*)&U[lane*SA + 120] = z;
    }

    s8v afp[4], aft0[4], aft1[4];

    // ---- tm1 L1 (2->100) + tangent seeds, direct to register A-frags
    #pragma unroll
    for (int ks = 0; ks < 4; ++ks) {
        int c0 = ks*32 + fq*8;
        s8v hv, t0v, t1v;
        #pragma unroll
        for (int e = 0; e < 8; ++e) {
            float w0 = wsf[F_TM1W1 + c0 + e], w1 = wsf[F_TM1W1 + 128 + c0 + e];
            float b  = wsf[F_TM1B1 + c0 + e];
            float pre = fmaf(xv.y, w1, fmaf(xv.x, w0, b));
            float h = tanh_fast(pre), dd = 1.f - h*h;
            hv[e] = f2bf(h); t0v[e] = f2bf(w0*dd); t1v[e] = f2bf(w1*dd);
        }
        afp[ks] = hv; aft0[ks] = t0v; aft1[ks] = t1v;
    }

    // ---- G1+E1: [48x128]@tm1_w2, tanh + tangent*(1-h^2), write U rows 0..47
    #pragma unroll
    for (int nt = 0; nt < 7; ++nt) {
        const short* bp = wsb + WT_TM1 + (nt*16 + fm)*128 + fq*8;
        s8v b0 = *(const s8v*)(bp), b1 = *(const s8v*)(bp + 32);
        s8v b2 = *(const s8v*)(bp + 64), b3 = *(const s8v*)(bp + 96);
        f4v cp = {0,0,0,0}, ct0 = {0,0,0,0}, ct1 = {0,0,0,0};
        cp  = mfma16(b0, afp[0], cp);   cp  = mfma16(b1, afp[1], cp);
        cp  = mfma16(b2, afp[2], cp);   cp  = mfma16(b3, afp[3], cp);
        ct0 = mfma16(b0, aft0[0], ct0); ct0 = mfma16(b1, aft0[1], ct0);
        ct0 = mfma16(b2, aft0[2], ct0); ct0 = mfma16(b3, aft0[3], ct0);
        ct1 = mfma16(b0, aft1[0], ct1); ct1 = mfma16(b1, aft1[1], ct1);
        ct1 = mfma16(b2, aft1[2], ct1); ct1 = mfma16(b3, aft1[3], ct1);
        int col0 = nt*16 + fq*4;
        float4 bb = *(const float4*)&wsf[F_TM1B2 + col0];
        float h0 = tanh_fast(cp[0]+bb.x), h1 = tanh_fast(cp[1]+bb.y);
        float h2 = tanh_fast(cp[2]+bb.z), h3 = tanh_fast(cp[3]+bb.w);
        float d0 = 1.f-h0*h0, d1 = 1.f-h1*h1, d2 = 1.f-h2*h2, d3 = 1.f-h3*h3;
        *(uint2*)&U[fm*SA + col0]      = pk4(h0, h1, h2, h3);
        *(uint2*)&U[(16+fm)*SA + col0] = pk4(ct0[0]*d0, ct0[1]*d1, ct0[2]*d2, ct0[3]*d3);
        *(uint2*)&U[(32+fm)*SA + col0] = pk4(ct1[0]*d0, ct1[1]*d1, ct1[2]*d2, ct1[3]*d3);
    }
    __syncthreads();

    // ---- L3 tm1 (100->2) via MFMA vs W3^T[16x128]
    {
        f4v d0 = {0,0,0,0}, d1 = {0,0,0,0}, d2 = {0,0,0,0};
        #pragma unroll
        for (int ks = 0; ks < 4; ++ks) {
            s8v bf = *(const s8v*)&wsb[WT_TM1L3 + fm*128 + ks*32 + fq*8];
            s8v a0 = *(const s8v*)&U[fm*SA + ks*32 + fq*8];
            s8v a1 = *(const s8v*)&U[(16+fm)*SA + ks*32 + fq*8];
            s8v a2 = *(const s8v*)&U[(32+fm)*SA + ks*32 + fq*8];
            d0 = mfma16(bf, a0, d0); d1 = mfma16(bf, a1, d1); d2 = mfma16(bf, a2, d2);
        }
        if (fq == 0) {
            WS[WY1 + fm*2+0] = d0[0] + tm1_b3[0] + xv.x;
            WS[WY1 + fm*2+1] = d0[1] + tm1_b3[1] + xv.y;
            WS[WDY1 + fm*4+0] = d1[0] + 1.f;
            WS[WDY1 + fm*4+1] = d1[1];
            WS[WDY1 + fm*4+2] = d2[0];
            WS[WDY1 + fm*4+3] = d2[1] + 1.f;
        }
    }
    __syncthreads();

    // ---- tm2 L1 (2->100) + tangent seeds
    {
        float y10 = WS[WY1 + fm*2], y11 = WS[WY1 + fm*2+1];
        float dy00 = WS[WDY1 + fm*4+0], dy01 = WS[WDY1 + fm*4+1];
        float dy10 = WS[WDY1 + fm*4+2], dy11 = WS[WDY1 + fm*4+3];
        #pragma unroll
        for (int ks = 0; ks < 4; ++ks) {
            int c0 = ks*32 + fq*8;
            s8v hv, t0v, t1v;
            #pragma unroll
            for (int e = 0; e < 8; ++e) {
                float w0 = wsf[F_TM2W1 + c0 + e], w1 = wsf[F_TM2W1 + 128 + c0 + e];
                float b  = wsf[F_TM2B1 + c0 + e];
                float pre = fmaf(y11, w1, fmaf(y10, w0, b));
                float g = pre > 0.f ? pre : (__expf(pre) - 1.f);
                float dd = pre > 0.f ? 1.f : (g + 1.f);
                hv[e] = f2bf(g);
                t0v[e] = f2bf((dy00*w0 + dy01*w1) * dd);
                t1v[e] = f2bf((dy10*w0 + dy11*w1) * dd);
            }
            afp[ks] = hv; aft0[ks] = t0v; aft1[ks] = t1v;
        }
    }

    // ---- G2+E2: [48x128]@tm2_w2, elu + tangent*elu'
    #pragma unroll
    for (int nt = 0; nt < 7; ++nt) {
        const short* bp = wsb + WT_TM2 + (nt*16 + fm)*128 + fq*8;
        s8v b0 = *(const s8v*)(bp), b1 = *(const s8v*)(bp + 32);
        s8v b2 = *(const s8v*)(bp + 64), b3 = *(const s8v*)(bp + 96);
        f4v cp = {0,0,0,0}, ct0 = {0,0,0,0}, ct1 = {0,0,0,0};
        cp  = mfma16(b0, afp[0], cp);   cp  = mfma16(b1, afp[1], cp);
        cp  = mfma16(b2, afp[2], cp);   cp  = mfma16(b3, afp[3], cp);
        ct0 = mfma16(b0, aft0[0], ct0); ct0 = mfma16(b1, aft0[1], ct0);
        ct0 = mfma16(b2, aft0[2], ct0); ct0 = mfma16(b3, aft0[3], ct0);
        ct1 = mfma16(b0, aft1[0], ct1); ct1 = mfma16(b1, aft1[1], ct1);
        ct1 = mfma16(b2, aft1[2], ct1); ct1 = mfma16(b3, aft1[3], ct1);
        int col0 = nt*16 + fq*4;
        float4 bb = *(const float4*)&wsf[F_TM2B2 + col0];
        float p0 = cp[0]+bb.x, p1 = cp[1]+bb.y, p2 = cp[2]+bb.z, p3 = cp[3]+bb.w;
        float g0 = p0 > 0.f ? p0 : (__expf(p0)-1.f), g1 = p1 > 0.f ? p1 : (__expf(p1)-1.f);
        float g2 = p2 > 0.f ? p2 : (__expf(p2)-1.f), g3 = p3 > 0.f ? p3 : (__expf(p3)-1.f);
        float d0 = p0 > 0.f ? 1.f : g0+1.f, d1 = p1 > 0.f ? 1.f : g1+1.f;
        float d2 = p2 > 0.f ? 1.f : g2+1.f, d3 = p3 > 0.f ? 1.f : g3+1.f;
        *(uint2*)&U[fm*SA + col0]      = pk4(g0, g1, g2, g3);
        *(uint2*)&U[(16+fm)*SA + col0] = pk4(ct0[0]*d0, ct0[1]*d1, ct0[2]*d2, ct0[3]*d3);
        *(uint2*)&U[(32+fm)*SA + col0] = pk4(ct1[0]*d0, ct1[1]*d1, ct1[2]*d2, ct1[3]*d3);
    }
    __syncthreads();

    // ---- L3 tm2 (100->2): s, sigma, ds
    {
        f4v d0 = {0,0,0,0}, d1 = {0,0,0,0}, d2 = {0,0,0,0};
        #pragma unroll
        for (int ks = 0; ks < 4; ++ks) {
            s8v bf = *(const s8v*)&wsb[WT_TM2L3 + fm*128 + ks*32 + fq*8];
            s8v a0 = *(const s8v*)&U[fm*SA + ks*32 + fq*8];
            s8v a1 = *(const s8v*)&U[(16+fm)*SA + ks*32 + fq*8];
            s8v a2 = *(const s8v*)&U[(32+fm)*SA + ks*32 + fq*8];
            d0 = mfma16(bf, a0, d0); d1 = mfma16(bf, a1, d1); d2 = mfma16(bf, a2, d2);
        }
        if (fq == 0) {
            #pragma unroll
            for (int i = 0; i < 2; ++i) {
                float spre = d0[i] + tm2_b3[i];
                WS[WSS + fm*2+i] = spre > 20.f ? spre : __logf(1.f + __expf(spre));
                WS[WSG + fm*2+i] = rcp_fast(1.f + __expf(-spre));
            }
            WS[WDS + fm*4+0] = d1[0]; WS[WDS + fm*4+1] = d1[1];
            WS[WDS + fm*4+2] = d2[0]; WS[WDS + fm*4+3] = d2[1];
        }
    }
    __syncthreads();

    // ---- J, ys
    {
        int pp = lane >> 2, d = (lane >> 1) & 1, ii = lane & 1;
        float sv = WS[WSS + pp*2+ii], sg = WS[WSG + pp*2+ii];
        float y1v = WS[WY1 + pp*2+ii], dyv = WS[WDY1 + pp*4 + d*2 + ii], dsv = WS[WDS + pp*4 + d*2 + ii];
        WS[WJ + pp*4 + ii*2 + d] = dsv*sg*y1v + (1.f + sv)*dyv;
        if (d == 0) WS[WYS + pp*2+ii] = (1.f + sv)*y1v - origin[ii];
    }
    __syncthreads();

    // ---- vs L1 (2->100)
    s8v afv[4];
    #pragma unroll
    for (int ks = 0; ks < 4; ++ks) {
        int c0 = ks*32 + fq*8;
        s8v hv;
        #pragma unroll
        for (int e = 0; e < 8; ++e) {
            float w0 = wsf[F_VSW1 + c0 + e], w1 = wsf[F_VSW1 + 128 + c0 + e];
            float b  = wsf[F_VSB1 + c0 + e];
            hv[e] = f2bf(leakyf(fmaf(xv.y, w1, fmaf(xv.x, w0, b))));
        }
        afv[ks] = hv;
    }

    // ---- G3+E3: [16x128]@vs_w2, leaky
    #pragma unroll
    for (int nt = 0; nt < 7; ++nt) {
        const short* bp = wsb + WT_VS + (nt*16 + fm)*128 + fq*8;
        s8v b0 = *(const s8v*)(bp), b1 = *(const s8v*)(bp + 32);
        s8v b2 = *(const s8v*)(bp + 64), b3 = *(const s8v*)(bp + 96);
        f4v cp = {0,0,0,0};
        cp = mfma16(b0, afv[0], cp); cp = mfma16(b1, afv[1], cp);
        cp = mfma16(b2, afv[2], cp); cp = mfma16(b3, afv[3], cp);
        int col0 = nt*16 + fq*4;
        float4 bb = *(const float4*)&wsf[F_VSB2 + col0];
        *(uint2*)&U[fm*SA + col0] = pk4(leakyf(cp[0]+bb.x), leakyf(cp[1]+bb.y),
                                        leakyf(cp[2]+bb.z), leakyf(cp[3]+bb.w));
    }
    __syncthreads();

    // ---- L3 vs (100->1)
    {
        f4v dv = {0,0,0,0};
        #pragma unroll
        for (int ks = 0; ks < 4; ++ks) {
            s8v bf = *(const s8v*)&wsb[WT_VSL3 + fm*128 + ks*32 + fq*8];
            s8v av = *(const s8v*)&U[fm*SA + ks*32 + fq*8];
            dv = mfma16(bf, av, dv);
        }
        if (fq == 0) WS[WLV + fm] = dv[0] + vs_b3[0];
    }
    __syncthreads();

    // ---- vv L1 (2->300), register A-frags + U copy (covers cols 0..319)
    s8v afw[10];
    {
        float ys0 = WS[WYS + fm*2], ys1 = WS[WYS + fm*2+1];
        #pragma unroll
        for (int ks = 0; ks < 10; ++ks) {
            int c0 = ks*32 + fq*8;
            s8v hv;
            #pragma unroll
            for (int e = 0; e < 8; ++e) {
                float w0 = wsf[F_VVW1 + c0 + e], w1 = wsf[F_VVW1 + 320 + c0 + e];
                float b  = wsf[F_VVB1 + c0 + e];
                hv[e] = f2bf(preluf(fmaf(ys1, w1, fmaf(ys0, w0, b)), a1v));
            }
            afw[ks] = hv;
            *(s8v*)&U[fm*SV + c0] = hv;
        }
    }

    // ---- G4+E4: [16x320]@vv_w2, prelu(a2)
    for (int nt = 0; nt < 19; ++nt) {
        const short* bp = wsb + WT_VV + (nt*16 + fm)*320 + fq*8;
        f4v cp = {0,0,0,0};
        #pragma unroll
        for (int ks = 0; ks < 10; ++ks)
            cp = mfma16(*(const s8v*)(bp + ks*32), afw[ks], cp);
        int col0 = nt*16 + fq*4;
        float4 bb = *(const float4*)&wsf[F_VVB2 + col0];
        *(uint2*)&U[fm*SV + col0] = pk4(preluf(cp[0]+bb.x, a2v), preluf(cp[1]+bb.y, a2v),
                                        preluf(cp[2]+bb.z, a2v), preluf(cp[3]+bb.w, a2v));
    }
    __syncthreads();

    // ---- L3 vv (300->2)
    {
        f4v dv = {0,0,0,0};
        #pragma unroll
        for (int ks = 0; ks < 10; ++ks) {
            s8v bf = *(const s8v*)&wsb[WT_VVL3 + fm*320 + ks*32 + fq*8];
            s8v av = *(const s8v*)&U[fm*SV + ks*32 + fq*8];
            dv = mfma16(bf, av, dv);
        }
        if (fq == 0) {
            WS[WDT + fm*2+0] = dv[0] + vv_b3[0];
            WS[WDT + fm*2+1] = dv[1] + vv_b3[1];
        }
    }
    __syncthreads();

    // ---- combine & store (lanes fq==0 hold point fm)
    if (fq == 0 && p < npts) {
        float y0 = WS[WYS + fm*2], y1v = WS[WYS + fm*2+1];
        float dt0 = WS[WDT + fm*2], dt1 = WS[WDT + fm*2+1];
        float ls = dt0*y0 + dt1*y1v;
        float Vq = y0*y0 + y1v*y1v;
        float coef = fmaxf(ls + 1e-4f*Vq, 0.f) * rcp_fast(Vq + 1e-12f);
        float yd0 = dt0 - coef*y0, yd1 = dt1 - coef*y1v;
        float inv_n = rcp_fast(fmaxf(sqrtf(yd0*yd0 + yd1*yd1), 1e-12f));
        float yn0 = yd0*inv_n, yn1 = yd1*inv_n;
        float Ja = WS[WJ + fm*4+0], Jb = WS[WJ + fm*4+1];
        float Jc = WS[WJ + fm*4+2], Jd = WS[WJ + fm*4+3];
        float invdet = rcp_fast(Ja*Jd - Jb*Jc);
        float xh0 = ( Jd*yn0 - Jb*yn1) * invdet;
        float xh1 = (-Jc*yn0 + Ja*yn1) * invdet;
        float lv = WS[WLV + fm];
        float2 o;
        o.x = (__expf(lv + xv.x) + 1e-12f) * xh0;
        o.y = (__expf(lv + xv.y) + 1e-12f) * xh1;
        *(float2*)&out[p*2] = o;
    }
}

extern "C" void kernel_launch(void* const* d_in, const int* in_sizes, int n_in,
                              void* d_out, int out_size, void* d_ws, size_t ws_size,
                              hipStream_t stream) {
    const float* x      = (const float*)d_in[0];
    const float* tm1_w1 = (const float*)d_in[1];
    const float* tm1_b1 = (const float*)d_in[2];
    const float* tm1_w2 = (const float*)d_in[3];
    const float* tm1_b2 = (const float*)d_in[4];
    const float* tm1_w3 = (const float*)d_in[5];
    const float* tm1_b3 = (const float*)d_in[6];
    const float* tm2_w1 = (const float*)d_in[7];
    const float* tm2_b1 = (const float*)d_in[8];
    const float* tm2_w2 = (const float*)d_in[9];
    const float* tm2_b2 = (const float*)d_in[10];
    const float* tm2_w3 = (const float*)d_in[11];
    const float* tm2_b3 = (const float*)d_in[12];
    const float* vv_w1  = (const float*)d_in[13];
    const float* vv_b1  = (const float*)d_in[14];
    const float* vv_a1  = (const float*)d_in[15];
    const float* vv_w2  = (const float*)d_in[16];
    const float* vv_b2  = (const float*)d_in[17];
    const float* vv_a2  = (const float*)d_in[18];
    const float* vv_w3  = (const float*)d_in[19];
    const float* vv_b3  = (const float*)d_in[20];
    const float* vs_w1  = (const float*)d_in[21];
    const float* vs_b1  = (const float*)d_in[22];
    const float* vs_w2  = (const float*)d_in[23];
    const float* vs_b2  = (const float*)d_in[24];
    const float* vs_w3  = (const float*)d_in[25];
    const float* vs_b3  = (const float*)d_in[26];

    float* out       = (float*)d_out;
    float* origin_ws = (float*)d_ws;                            // 2 floats
    short* wsb       = (short*)((char*)d_ws + 64);              // bf16 regions
    float* wsf       = (float*)((char*)d_ws + 64 + NSHORT*2);   // fp32 padded region
    const int npts = in_sizes[0] / 2;
    const int nblk = (npts + 63) / 64;

    ngdv_prep<<<604, 256, 0, stream>>>(
        tm1_w1, tm1_b1, tm1_w2, tm1_b2, tm1_w3, tm1_b3,
        tm2_w1, tm2_b1, tm2_w2, tm2_b2, tm2_w3, tm2_b3,
        vs_w1, vs_b1, vs_w2, vs_b2, vs_w3,
        vv_w1, vv_b1, vv_w2, vv_b2, vv_w3,
        wsb, wsf, origin_ws);

    ngdv_main<<<nblk, 256, 0, stream>>>(
        x, tm1_b3, tm2_b3, vs_b3, vv_b3, vv_a1, vv_a2,
        wsb, wsf, origin_ws, out, npts);
}